// Round 2
// baseline (24907.523 us; speedup 1.0000x reference)
//
#include <hip/hip_runtime.h>
#include <hip/hip_bf16.h>
#include <cstddef>

// Problem constants
#define NT     12544   // B*T tokens
#define BATCH  64
#define TSEQ   196
#define DMODEL 2048
#define NH     32
#define NKVH   8
#define HDIM   64
#define IMLP   8192
#define QDIMC  512
#define PDIMC  128

// ---------------------------------------------------------------------------
// RMSNorm: one block (256 thr) per token row, D=2048 -> 8 floats/thread
// ---------------------------------------------------------------------------
__global__ __launch_bounds__(256) void rmsnorm_kernel(const float* __restrict__ x,
                                                      const float* __restrict__ w,
                                                      float* __restrict__ y) {
    int row = blockIdx.x;
    const float* xr = x + (size_t)row * DMODEL;
    float* yr = y + (size_t)row * DMODEL;
    int t = threadIdx.x;
    float4 v0 = ((const float4*)xr)[t];
    float4 v1 = ((const float4*)xr)[t + 256];
    float ss = v0.x*v0.x + v0.y*v0.y + v0.z*v0.z + v0.w*v0.w
             + v1.x*v1.x + v1.y*v1.y + v1.z*v1.z + v1.w*v1.w;
    #pragma unroll
    for (int off = 32; off; off >>= 1) ss += __shfl_xor(ss, off);
    __shared__ float red[4];
    int wave = t >> 6, lane = t & 63;
    if (lane == 0) red[wave] = ss;
    __syncthreads();
    float tot = red[0] + red[1] + red[2] + red[3];
    float rs = rsqrtf(tot * (1.0f / DMODEL) + 1e-5f);
    float4 w0 = ((const float4*)w)[t];
    float4 w1 = ((const float4*)w)[t + 256];
    float4 o0, o1;
    o0.x = v0.x*rs*w0.x; o0.y = v0.y*rs*w0.y; o0.z = v0.z*rs*w0.z; o0.w = v0.w*rs*w0.w;
    o1.x = v1.x*rs*w1.x; o1.y = v1.y*rs*w1.y; o1.z = v1.z*rs*w1.z; o1.w = v1.w*rs*w1.w;
    ((float4*)yr)[t] = o0;
    ((float4*)yr)[t + 256] = o1;
}

// ---------------------------------------------------------------------------
// Tiled fp32 SGEMM, 64x64 tile, BK=16, 256 threads, 4x4 microtile.
// EPI: 0 -> C = A@B ; 1 -> C = A@B + S ; 2 -> C += A@B
// Requires M%64==0, N%64==0, K%16==0 (true for all calls here).
// ---------------------------------------------------------------------------
template <int EPI>
__global__ __launch_bounds__(256) void sgemm_kernel(const float* __restrict__ A,
                                                    const float* __restrict__ B,
                                                    const float* __restrict__ S,
                                                    float* __restrict__ C,
                                                    int M, int N, int K,
                                                    int lda, int ldb, int ldc) {
    __shared__ float As[16][68];   // A^T tile, padded stride 68
    __shared__ float Bs[16][64];
    int tid = threadIdx.x;
    int tx = tid & 15, ty = tid >> 4;
    int bm = blockIdx.y * 64;
    int bn = blockIdx.x * 64;
    int ar = tid >> 2, ac = (tid & 3) * 4;   // A tile coords
    int br = tid >> 4, bc = (tid & 15) * 4;  // B tile coords
    float acc[4][4] = {};
    for (int k0 = 0; k0 < K; k0 += 16) {
        float4 av = *(const float4*)&A[(size_t)(bm + ar) * lda + k0 + ac];
        float4 bv = *(const float4*)&B[(size_t)(k0 + br) * ldb + bn + bc];
        __syncthreads();
        As[ac + 0][ar] = av.x; As[ac + 1][ar] = av.y;
        As[ac + 2][ar] = av.z; As[ac + 3][ar] = av.w;
        *(float4*)&Bs[br][bc] = bv;
        __syncthreads();
        #pragma unroll
        for (int kk = 0; kk < 16; ++kk) {
            float4 a = *(const float4*)&As[kk][ty * 4];
            float4 b = *(const float4*)&Bs[kk][tx * 4];
            acc[0][0] += a.x * b.x; acc[0][1] += a.x * b.y; acc[0][2] += a.x * b.z; acc[0][3] += a.x * b.w;
            acc[1][0] += a.y * b.x; acc[1][1] += a.y * b.y; acc[1][2] += a.y * b.z; acc[1][3] += a.y * b.w;
            acc[2][0] += a.z * b.x; acc[2][1] += a.z * b.y; acc[2][2] += a.z * b.z; acc[2][3] += a.z * b.w;
            acc[3][0] += a.w * b.x; acc[3][1] += a.w * b.y; acc[3][2] += a.w * b.z; acc[3][3] += a.w * b.w;
        }
    }
    #pragma unroll
    for (int i = 0; i < 4; ++i) {
        size_t off = (size_t)(bm + ty * 4 + i) * ldc + bn + tx * 4;
        float4 r = make_float4(acc[i][0], acc[i][1], acc[i][2], acc[i][3]);
        if (EPI == 1) {
            float4 s = *(const float4*)&S[off];
            r.x += s.x; r.y += s.y; r.z += s.z; r.w += s.w;
        } else if (EPI == 2) {
            float4 s = *(const float4*)&C[off];
            r.x += s.x; r.y += s.y; r.z += s.z; r.w += s.w;
        }
        *(float4*)&C[off] = r;
    }
}

// ---------------------------------------------------------------------------
// Dual GEMM for SwiGLU: C = silu(A@Bg) * (A@Bu). Same tiling as sgemm_kernel.
// ---------------------------------------------------------------------------
__global__ __launch_bounds__(256) void dualgemm_swiglu_kernel(const float* __restrict__ A,
                                                              const float* __restrict__ Bg,
                                                              const float* __restrict__ Bu,
                                                              float* __restrict__ C,
                                                              int M, int N, int K,
                                                              int lda, int ldb, int ldc) {
    __shared__ float As[16][68];
    __shared__ float Bgs[16][64];
    __shared__ float Bus[16][64];
    int tid = threadIdx.x;
    int tx = tid & 15, ty = tid >> 4;
    int bm = blockIdx.y * 64;
    int bn = blockIdx.x * 64;
    int ar = tid >> 2, ac = (tid & 3) * 4;
    int br = tid >> 4, bc = (tid & 15) * 4;
    float gacc[4][4] = {};
    float uacc[4][4] = {};
    for (int k0 = 0; k0 < K; k0 += 16) {
        float4 av = *(const float4*)&A[(size_t)(bm + ar) * lda + k0 + ac];
        float4 gv = *(const float4*)&Bg[(size_t)(k0 + br) * ldb + bn + bc];
        float4 uv = *(const float4*)&Bu[(size_t)(k0 + br) * ldb + bn + bc];
        __syncthreads();
        As[ac + 0][ar] = av.x; As[ac + 1][ar] = av.y;
        As[ac + 2][ar] = av.z; As[ac + 3][ar] = av.w;
        *(float4*)&Bgs[br][bc] = gv;
        *(float4*)&Bus[br][bc] = uv;
        __syncthreads();
        #pragma unroll
        for (int kk = 0; kk < 16; ++kk) {
            float4 a = *(const float4*)&As[kk][ty * 4];
            float4 g = *(const float4*)&Bgs[kk][tx * 4];
            float4 u = *(const float4*)&Bus[kk][tx * 4];
            gacc[0][0] += a.x * g.x; gacc[0][1] += a.x * g.y; gacc[0][2] += a.x * g.z; gacc[0][3] += a.x * g.w;
            gacc[1][0] += a.y * g.x; gacc[1][1] += a.y * g.y; gacc[1][2] += a.y * g.z; gacc[1][3] += a.y * g.w;
            gacc[2][0] += a.z * g.x; gacc[2][1] += a.z * g.y; gacc[2][2] += a.z * g.z; gacc[2][3] += a.z * g.w;
            gacc[3][0] += a.w * g.x; gacc[3][1] += a.w * g.y; gacc[3][2] += a.w * g.z; gacc[3][3] += a.w * g.w;
            uacc[0][0] += a.x * u.x; uacc[0][1] += a.x * u.y; uacc[0][2] += a.x * u.z; uacc[0][3] += a.x * u.w;
            uacc[1][0] += a.y * u.x; uacc[1][1] += a.y * u.y; uacc[1][2] += a.y * u.z; uacc[1][3] += a.y * u.w;
            uacc[2][0] += a.z * u.x; uacc[2][1] += a.z * u.y; uacc[2][2] += a.z * u.z; uacc[2][3] += a.z * u.w;
            uacc[3][0] += a.w * u.x; uacc[3][1] += a.w * u.y; uacc[3][2] += a.w * u.z; uacc[3][3] += a.w * u.w;
        }
    }
    #pragma unroll
    for (int i = 0; i < 4; ++i) {
        size_t off = (size_t)(bm + ty * 4 + i) * ldc + bn + tx * 4;
        float4 r;
        float g0 = gacc[i][0], g1 = gacc[i][1], g2 = gacc[i][2], g3 = gacc[i][3];
        r.x = g0 / (1.0f + expf(-g0)) * uacc[i][0];
        r.y = g1 / (1.0f + expf(-g1)) * uacc[i][1];
        r.z = g2 / (1.0f + expf(-g2)) * uacc[i][2];
        r.w = g3 / (1.0f + expf(-g3)) * uacc[i][3];
        *(float4*)&C[off] = r;
    }
}

// ---------------------------------------------------------------------------
// RoPE in-place. x: [NT, nh, 64]; pair (i, i+32) rotated by angle t*theta^(-i/32)
// ---------------------------------------------------------------------------
__global__ __launch_bounds__(256) void rope_kernel(float* __restrict__ x, int nh, int total) {
    int idx = blockIdx.x * 256 + threadIdx.x;
    if (idx >= total) return;
    int i = idx & 31;
    int head_tok = idx >> 5;          // tok*nh + head
    int tok = head_tok / nh;
    int t = tok % TSEQ;
    float inv = powf(500000.0f, -(float)i * (1.0f / 32.0f));
    float f = (float)t * inv;
    float c = cosf(f), s = sinf(f);
    float* p = x + (size_t)head_tok * HDIM + i;
    float x1 = p[0], x2 = p[32];
    p[0]  = x1 * c - x2 * s;
    p[32] = x2 * c + x1 * s;
}

// ---------------------------------------------------------------------------
// GQA causal attention. One block per (b, kvh); 4 waves handle 4 q-heads x T rows.
// K staged in LDS (padded stride 65); V streamed from global (L1/L2 resident).
// q layout [NT, NH, 64], k/v [NT, NKVH, 64], o [NT, NH, 64].
// ---------------------------------------------------------------------------
__global__ __launch_bounds__(256) void attn_kernel(const float* __restrict__ q,
                                                   const float* __restrict__ k,
                                                   const float* __restrict__ v,
                                                   float* __restrict__ o) {
    __shared__ float ks[TSEQ][65];    // 50.96 KB
    __shared__ float qs[4][64];
    __shared__ float ps[4][TSEQ];
    int b = blockIdx.x >> 3;
    int kvh = blockIdx.x & 7;
    int tid = threadIdx.x, wave = tid >> 6, lane = tid & 63;

    for (int idx = tid; idx < TSEQ * HDIM; idx += 256) {
        int tk = idx >> 6, hd = idx & 63;
        ks[tk][hd] = k[((size_t)(b * TSEQ + tk) * NKVH + kvh) * HDIM + hd];
    }
    __syncthreads();

    const float* vb = v + ((size_t)(b * TSEQ) * NKVH + kvh) * HDIM + lane;
    for (int r = wave; r < 4 * TSEQ; r += 4) {
        int hl = r / TSEQ;
        int tq = r - hl * TSEQ;
        int h = kvh * 4 + hl;
        qs[wave][lane] = q[((size_t)(b * TSEQ + tq) * NH + h) * HDIM + lane] * 0.125f;
        float sreg[4];
        float m = -INFINITY;
        #pragma unroll
        for (int c = 0; c < 4; ++c) {
            int tk = c * 64 + lane;
            float sc = -INFINITY;
            if (tk <= tq) {
                float a = 0.f;
                #pragma unroll 16
                for (int hd = 0; hd < 64; ++hd) a += qs[wave][hd] * ks[tk][hd];
                sc = a;
            }
            sreg[c] = sc;
            m = fmaxf(m, sc);
        }
        #pragma unroll
        for (int off = 32; off; off >>= 1) m = fmaxf(m, __shfl_xor(m, off));
        float l = 0.f;
        #pragma unroll
        for (int c = 0; c < 4; ++c) {
            int tk = c * 64 + lane;
            float p = __expf(sreg[c] - m);   // -inf -> 0
            if (tk < TSEQ) ps[wave][tk] = p;
            l += p;
        }
        #pragma unroll
        for (int off = 32; off; off >>= 1) l += __shfl_xor(l, off);
        float acc = 0.f;
        for (int tk = 0; tk <= tq; ++tk)
            acc += ps[wave][tk] * vb[(size_t)tk * (NKVH * HDIM)];
        o[((size_t)(b * TSEQ + tq) * NH + h) * HDIM + lane] = acc / l;
    }
}

// ---------------------------------------------------------------------------
// zq = normalize(query @ Wqh) : 64 blocks x 128 threads
// ---------------------------------------------------------------------------
__global__ __launch_bounds__(128) void zq_kernel(const float* __restrict__ query,
                                                 const float* __restrict__ Wqh,
                                                 float* __restrict__ zq) {
    int b = blockIdx.x, j = threadIdx.x;
    const float* qr = query + (size_t)b * QDIMC;
    float acc = 0.f;
    for (int kk = 0; kk < QDIMC; ++kk) acc += qr[kk] * Wqh[(size_t)kk * PDIMC + j];
    float ss = acc * acc;
    #pragma unroll
    for (int off = 32; off; off >>= 1) ss += __shfl_xor(ss, off);
    __shared__ float red[2];
    if ((j & 63) == 0) red[j >> 6] = ss;
    __syncthreads();
    zq[(size_t)b * PDIMC + j] = acc * rsqrtf(red[0] + red[1]);
}

// ---------------------------------------------------------------------------
// out[b,t] = dot(normalize(zp[b,t]), zq[b]) * scale + bias : 1 block/token
// ---------------------------------------------------------------------------
__global__ __launch_bounds__(128) void head_kernel(const float* __restrict__ zp,
                                                   const float* __restrict__ zq,
                                                   const float* __restrict__ scale,
                                                   const float* __restrict__ bias,
                                                   float* __restrict__ out) {
    int row = blockIdx.x;
    int b = row / TSEQ;
    int j = threadIdx.x;
    float zpv = zp[(size_t)row * PDIMC + j];
    float zqv = zq[(size_t)b * PDIMC + j];
    float ss = zpv * zpv, dd = zpv * zqv;
    #pragma unroll
    for (int off = 32; off; off >>= 1) { ss += __shfl_xor(ss, off); dd += __shfl_xor(dd, off); }
    __shared__ float rs2[2], rd2[2];
    if ((j & 63) == 0) { rs2[j >> 6] = ss; rd2[j >> 6] = dd; }
    __syncthreads();
    if (j == 0)
        out[row] = (rd2[0] + rd2[1]) * rsqrtf(rs2[0] + rs2[1]) * scale[0] + bias[0];
}

// ---------------------------------------------------------------------------
extern "C" void kernel_launch(void* const* d_in, const int* in_sizes, int n_in,
                              void* d_out, int out_size, void* d_ws, size_t ws_size,
                              hipStream_t stream) {
    const float* x       = (const float*)d_in[0];   // [NT, D]
    const float* query   = (const float*)d_in[1];   // [64, 512]
    const float* Wq      = (const float*)d_in[2];   // [D, 2048]
    const float* Wk      = (const float*)d_in[3];   // [D, 512]
    const float* Wv      = (const float*)d_in[4];   // [D, 512]
    const float* Wo      = (const float*)d_in[5];   // [2048, D]
    const float* Wgate   = (const float*)d_in[6];   // [D, 8192]
    const float* Wup     = (const float*)d_in[7];   // [D, 8192]
    const float* Wdown   = (const float*)d_in[8];   // [8192, D]
    const float* w_ln_in = (const float*)d_in[9];
    const float* w_ln_po = (const float*)d_in[10];
    const float* w_norm  = (const float*)d_in[11];
    const float* Wp      = (const float*)d_in[12];  // [D, 128]
    const float* Wqh     = (const float*)d_in[13];  // [512, 128]
    const float* scale   = (const float*)d_in[14];
    const float* bias    = (const float*)d_in[15];
    float* out = (float*)d_out;

    // Workspace carve-up (fp32): NT*5120 floats = 245 MiB total.
    //   buf0 [NT,2048] : h -> o -> h2 -> x3
    //   buf1 [NT,2048] : q -> x1 (+= mlp) = x2 -> {zp, zq}
    //   buf2 [NT,512]  : k   \__ after attention reused together as
    //   buf3 [NT,512]  : v   /   mlp act chunk [NT,1024]
    float* buf0 = (float*)d_ws;
    float* buf1 = buf0 + (size_t)NT * DMODEL;
    float* buf2 = buf1 + (size_t)NT * DMODEL;
    float* buf3 = buf2 + (size_t)NT * (NKVH * HDIM);
    float* mlp_act = buf2;                       // [NT, 1024] (overlaps buf2+buf3)
    float* zp = buf1;                            // [NT, 128]
    float* zq = buf1 + (size_t)NT * PDIMC;       // [64, 128]

    // 1. h = rmsnorm(x, w_ln_in)
    rmsnorm_kernel<<<NT, 256, 0, stream>>>(x, w_ln_in, buf0);
    // 2. q/k/v projections
    sgemm_kernel<0><<<dim3(2048 / 64, NT / 64), 256, 0, stream>>>(
        buf0, Wq, nullptr, buf1, NT, 2048, DMODEL, DMODEL, 2048, 2048);
    sgemm_kernel<0><<<dim3(512 / 64, NT / 64), 256, 0, stream>>>(
        buf0, Wk, nullptr, buf2, NT, 512, DMODEL, DMODEL, 512, 512);
    sgemm_kernel<0><<<dim3(512 / 64, NT / 64), 256, 0, stream>>>(
        buf0, Wv, nullptr, buf3, NT, 512, DMODEL, DMODEL, 512, 512);
    // 3. RoPE on q and k (in place)
    {
        int tq = NT * NH * 32;
        rope_kernel<<<(tq + 255) / 256, 256, 0, stream>>>(buf1, NH, tq);
        int tk = NT * NKVH * 32;
        rope_kernel<<<(tk + 255) / 256, 256, 0, stream>>>(buf2, NKVH, tk);
    }
    // 4. attention -> o (buf0; h dead)
    attn_kernel<<<BATCH * NKVH, 256, 0, stream>>>(buf1, buf2, buf3, buf0);
    // 5. x1 = o @ Wo + x  -> buf1 (q dead)
    sgemm_kernel<1><<<dim3(2048 / 64, NT / 64), 256, 0, stream>>>(
        buf0, Wo, x, buf1, NT, 2048, 2048, 2048, 2048, 2048);
    // 6. h2 = rmsnorm(x1, w_ln_post) -> buf0 (o dead)
    rmsnorm_kernel<<<NT, 256, 0, stream>>>(buf1, w_ln_po, buf0);
    // 7. SwiGLU MLP, I chunked by 1024 (act chunk reuses dead k/v buffers);
    //    x2 accumulates in place onto x1 (buf1)
    for (int c = 0; c < 8; ++c) {
        dualgemm_swiglu_kernel<<<dim3(1024 / 64, NT / 64), 256, 0, stream>>>(
            buf0, Wgate + (size_t)c * 1024, Wup + (size_t)c * 1024, mlp_act,
            NT, 1024, DMODEL, DMODEL, IMLP, 1024);
        sgemm_kernel<2><<<dim3(2048 / 64, NT / 64), 256, 0, stream>>>(
            mlp_act, Wdown + (size_t)c * 1024 * DMODEL, nullptr, buf1,
            NT, 2048, 1024, 1024, DMODEL, 2048);
    }
    // 8. x3 = rmsnorm(x2, w_norm) -> buf0
    rmsnorm_kernel<<<NT, 256, 0, stream>>>(buf1, w_norm, buf0);
    // 9. zp = x3 @ Wp -> buf1 (x2 dead)
    sgemm_kernel<0><<<dim3(PDIMC / 64, NT / 64), 256, 0, stream>>>(
        buf0, Wp, nullptr, zp, NT, PDIMC, DMODEL, DMODEL, PDIMC, PDIMC);
    // 10. zq = normalize(query @ Wqh)
    zq_kernel<<<BATCH, 128, 0, stream>>>(query, Wqh, zq);
    // 11. out = cos-sim head
    head_kernel<<<NT, 128, 0, stream>>>(zp, zq, scale, bias, out);
}

// Round 3
// 6427.078 us; speedup vs baseline: 3.8754x; 3.8754x over previous
//
#include <hip/hip_runtime.h>
#include <hip/hip_bf16.h>
#include <cstddef>

// Problem constants
#define NT     12544   // B*T tokens
#define BATCH  64
#define TSEQ   196
#define DMODEL 2048
#define NH     32
#define NKVH   8
#define HDIM   64
#define IMLP   8192
#define QDIMC  512
#define PDIMC  128

typedef __bf16 bf16x8 __attribute__((ext_vector_type(8)));
typedef float f32x4 __attribute__((ext_vector_type(4)));

// ---------------------------------------------------------------------------
// async global->LDS, 16B per lane (dest = wave-uniform base + lane*16)
// ---------------------------------------------------------------------------
__device__ __forceinline__ void gload_lds16(const void* g, void* l) {
    __builtin_amdgcn_global_load_lds(
        (__attribute__((address_space(1))) void*)g,
        (__attribute__((address_space(3))) void*)l, 16, 0, 0);
}

// ---------------------------------------------------------------------------
// bf16 MFMA GEMM: C[M,N] = A[M,K] @ B[K,N], B given pre-transposed BT[N,K].
// 128x128 tile, BK=32, 256 thr (4 waves, each 64x64 = 4x4 mfma_16x16x32 tiles).
// LDS layout: K-panel slots: slot(k2,m) = k2*128+m holds 8 bf16 (k=k2*8..+7)
// -> staging matches global_load_lds lane order AND ds_read_b128 conflict-free.
// EPI: 0 -> C bf16 = acc ; 1 -> C fp32 = acc + S ; 2 -> C fp32 += acc
// Requires M%128==0, N%128==0, K%32==0 (true for all calls here).
// ---------------------------------------------------------------------------
template <int EPI>
__global__ __launch_bounds__(256) void mfma_gemm_kernel(
    const __hip_bfloat16* __restrict__ A,
    const __hip_bfloat16* __restrict__ BT,
    const float* __restrict__ S,
    void* __restrict__ Cout,
    int K, int lda, int ldb, int ldc) {
    __shared__ __align__(16) __hip_bfloat16 Asb[4096];   // 8 KB
    __shared__ __align__(16) __hip_bfloat16 Bsb[4096];   // 8 KB
    const int tid  = threadIdx.x;
    const int lane = tid & 63;
    const int wave = tid >> 6;
    const int quad = lane >> 4;
    const int l16  = lane & 15;
    const int bm = blockIdx.y * 128;
    const int bn = blockIdx.x * 128;
    const int wm = (wave >> 1) * 64;
    const int wn = (wave & 1) * 64;
    // staging: call c covers slots c*256+tid -> k2 = c*2 + (tid>>7), m = tid&127
    const int sm = tid & 127;
    const int sk = tid >> 7;
    const __hip_bfloat16* ga = A  + (size_t)(bm + sm) * lda + sk * 8;
    const __hip_bfloat16* gb = BT + (size_t)(bn + sm) * ldb + sk * 8;
    __hip_bfloat16* lA0 = Asb + wave * 512;        // wave-uniform LDS bases
    __hip_bfloat16* lB0 = Bsb + wave * 512;
    __hip_bfloat16* lA1 = lA0 + 2048;
    __hip_bfloat16* lB1 = lB0 + 2048;
    f32x4 acc[4][4] = {};
    for (int k0 = 0; k0 < K; k0 += 32) {
        __syncthreads();                            // LDS reuse guard
        gload_lds16(ga + k0,      lA0);
        gload_lds16(gb + k0,      lB0);
        gload_lds16(ga + k0 + 16, lA1);
        gload_lds16(gb + k0 + 16, lB1);
        __syncthreads();                            // drains vmcnt before barrier
        const bf16x8* Af = (const bf16x8*)Asb;
        const bf16x8* Bf = (const bf16x8*)Bsb;
        bf16x8 av[4], bv[4];
        #pragma unroll
        for (int t = 0; t < 4; ++t) {
            av[t] = Af[quad * 128 + wm + t * 16 + l16];
            bv[t] = Bf[quad * 128 + wn + t * 16 + l16];
        }
        #pragma unroll
        for (int tm = 0; tm < 4; ++tm)
            #pragma unroll
            for (int tn = 0; tn < 4; ++tn)
                acc[tm][tn] = __builtin_amdgcn_mfma_f32_16x16x32_bf16(
                    av[tm], bv[tn], acc[tm][tn], 0, 0, 0);
    }
    // epilogue: C[row = bm+wm+tm*16+quad*4+r][col = bn+wn+tn*16+l16]
    #pragma unroll
    for (int tm = 0; tm < 4; ++tm) {
        #pragma unroll
        for (int tn = 0; tn < 4; ++tn) {
            const int col = bn + wn + tn * 16 + l16;
            #pragma unroll
            for (int r = 0; r < 4; ++r) {
                const int row = bm + wm + tm * 16 + quad * 4 + r;
                const size_t off = (size_t)row * ldc + col;
                const float vv = acc[tm][tn][r];
                if (EPI == 0)      ((__hip_bfloat16*)Cout)[off] = __float2bfloat16(vv);
                else if (EPI == 1) ((float*)Cout)[off] = vv + S[off];
                else               ((float*)Cout)[off] += vv;
            }
        }
    }
}

// ---------------------------------------------------------------------------
// fp32 W[K,N] (leading dim ldw) -> bf16 WT[N,K] (leading dim Kd). 32x32 tiles.
// ---------------------------------------------------------------------------
__global__ __launch_bounds__(256) void transpose_cast_kernel(
    const float* __restrict__ W, __hip_bfloat16* __restrict__ WT,
    int Kd, int ldw) {
    __shared__ float tile[32][33];
    const int k0 = blockIdx.x * 32;
    const int n0 = blockIdx.y * 32;
    const int t = threadIdx.x;
    const int r = t >> 3, c4 = (t & 7) * 4;
    float4 v = *(const float4*)&W[(size_t)(k0 + r) * ldw + n0 + c4];
    tile[r][c4] = v.x; tile[r][c4 + 1] = v.y; tile[r][c4 + 2] = v.z; tile[r][c4 + 3] = v.w;
    __syncthreads();
    __hip_bfloat162 p0, p1;
    p0.x = __float2bfloat16(tile[c4][r]);     p0.y = __float2bfloat16(tile[c4 + 1][r]);
    p1.x = __float2bfloat16(tile[c4 + 2][r]); p1.y = __float2bfloat16(tile[c4 + 3][r]);
    __hip_bfloat16* o = &WT[(size_t)(n0 + r) * Kd + k0 + c4];
    ((__hip_bfloat162*)o)[0] = p0;
    ((__hip_bfloat162*)o)[1] = p1;
}

// ---------------------------------------------------------------------------
// RMSNorm fp32 in -> bf16 out. One block per token row.
// ---------------------------------------------------------------------------
__global__ __launch_bounds__(256) void rmsnorm_bf16_kernel(const float* __restrict__ x,
                                                           const float* __restrict__ w,
                                                           __hip_bfloat16* __restrict__ y) {
    const int row = blockIdx.x;
    const float* xr = x + (size_t)row * DMODEL;
    __hip_bfloat16* yr = y + (size_t)row * DMODEL;
    const int t = threadIdx.x;
    float4 v0 = ((const float4*)xr)[t];
    float4 v1 = ((const float4*)xr)[t + 256];
    float ss = v0.x*v0.x + v0.y*v0.y + v0.z*v0.z + v0.w*v0.w
             + v1.x*v1.x + v1.y*v1.y + v1.z*v1.z + v1.w*v1.w;
    #pragma unroll
    for (int off = 32; off; off >>= 1) ss += __shfl_xor(ss, off);
    __shared__ float red[4];
    if ((t & 63) == 0) red[t >> 6] = ss;
    __syncthreads();
    const float rs = rsqrtf((red[0] + red[1] + red[2] + red[3]) * (1.0f / DMODEL) + 1e-5f);
    float4 w0 = ((const float4*)w)[t];
    float4 w1 = ((const float4*)w)[t + 256];
    __hip_bfloat162 a, b, c, d;
    a.x = __float2bfloat16(v0.x * rs * w0.x); a.y = __float2bfloat16(v0.y * rs * w0.y);
    b.x = __float2bfloat16(v0.z * rs * w0.z); b.y = __float2bfloat16(v0.w * rs * w0.w);
    c.x = __float2bfloat16(v1.x * rs * w1.x); c.y = __float2bfloat16(v1.y * rs * w1.y);
    d.x = __float2bfloat16(v1.z * rs * w1.z); d.y = __float2bfloat16(v1.w * rs * w1.w);
    __hip_bfloat162* o0 = (__hip_bfloat162*)&yr[4 * t];
    o0[0] = a; o0[1] = b;
    __hip_bfloat162* o1 = (__hip_bfloat162*)&yr[1024 + 4 * t];
    o1[0] = c; o1[1] = d;
}

// ---------------------------------------------------------------------------
// SwiGLU elementwise: o = silu(g) * u (bf16, 2 elems/thread; o may alias g)
// ---------------------------------------------------------------------------
__global__ __launch_bounds__(256) void silu_mul_kernel(const __hip_bfloat16* __restrict__ g,
                                                       const __hip_bfloat16* __restrict__ u,
                                                       __hip_bfloat16* __restrict__ o, int n2) {
    const int i = blockIdx.x * 256 + threadIdx.x;
    if (i >= n2) return;
    __hip_bfloat162 gv = ((const __hip_bfloat162*)g)[i];
    __hip_bfloat162 uv = ((const __hip_bfloat162*)u)[i];
    const float gx = __bfloat162float(gv.x), gy = __bfloat162float(gv.y);
    __hip_bfloat162 ov;
    ov.x = __float2bfloat16(gx / (1.f + __expf(-gx)) * __bfloat162float(uv.x));
    ov.y = __float2bfloat16(gy / (1.f + __expf(-gy)) * __bfloat162float(uv.y));
    ((__hip_bfloat162*)o)[i] = ov;
}

// ---------------------------------------------------------------------------
// RoPE in-place on bf16. x: [NT, nh, 64]; pair (i, i+32), angle t*500000^(-i/32)
// ---------------------------------------------------------------------------
__global__ __launch_bounds__(256) void rope_bf16_kernel(__hip_bfloat16* __restrict__ x,
                                                        int nh, int total) {
    const int idx = blockIdx.x * 256 + threadIdx.x;
    if (idx >= total) return;
    const int i = idx & 31;
    const int head_tok = idx >> 5;
    const int t = (head_tok / nh) % TSEQ;
    const float f = (float)t * powf(500000.0f, -(float)i * (1.0f / 32.0f));
    const float c = cosf(f), s = sinf(f);
    __hip_bfloat16* p = x + (size_t)head_tok * HDIM + i;
    const float x1 = __bfloat162float(p[0]), x2 = __bfloat162float(p[32]);
    p[0]  = __float2bfloat16(x1 * c - x2 * s);
    p[32] = __float2bfloat16(x2 * c + x1 * s);
}

// ---------------------------------------------------------------------------
// GQA causal attention (bf16 in/out, fp32 math). One block per (b, kvh).
// ---------------------------------------------------------------------------
__global__ __launch_bounds__(256) void attn_kernel(const __hip_bfloat16* __restrict__ q,
                                                   const __hip_bfloat16* __restrict__ k,
                                                   const __hip_bfloat16* __restrict__ v,
                                                   __hip_bfloat16* __restrict__ o) {
    __shared__ float ks[TSEQ][65];
    __shared__ float qs[4][64];
    __shared__ float ps[4][TSEQ];
    const int b = blockIdx.x >> 3;
    const int kvh = blockIdx.x & 7;
    const int tid = threadIdx.x, wave = tid >> 6, lane = tid & 63;

    for (int idx = tid; idx < TSEQ * HDIM; idx += 256) {
        int tk = idx >> 6, hd = idx & 63;
        ks[tk][hd] = __bfloat162float(k[((size_t)(b * TSEQ + tk) * NKVH + kvh) * HDIM + hd]);
    }
    __syncthreads();

    const __hip_bfloat16* vb = v + ((size_t)(b * TSEQ) * NKVH + kvh) * HDIM + lane;
    for (int r = wave; r < 4 * TSEQ; r += 4) {
        const int hl = r / TSEQ;
        const int tq = r - hl * TSEQ;
        const int h = kvh * 4 + hl;
        qs[wave][lane] = __bfloat162float(q[((size_t)(b * TSEQ + tq) * NH + h) * HDIM + lane]) * 0.125f;
        float sreg[4];
        float m = -INFINITY;
        #pragma unroll
        for (int c = 0; c < 4; ++c) {
            const int tk = c * 64 + lane;
            float sc = -INFINITY;
            if (tk <= tq) {
                float a = 0.f;
                #pragma unroll 16
                for (int hd = 0; hd < 64; ++hd) a += qs[wave][hd] * ks[tk][hd];
                sc = a;
            }
            sreg[c] = sc;
            m = fmaxf(m, sc);
        }
        #pragma unroll
        for (int off = 32; off; off >>= 1) m = fmaxf(m, __shfl_xor(m, off));
        float l = 0.f;
        #pragma unroll
        for (int c = 0; c < 4; ++c) {
            const int tk = c * 64 + lane;
            const float p = __expf(sreg[c] - m);
            if (tk < TSEQ) ps[wave][tk] = p;
            l += p;
        }
        #pragma unroll
        for (int off = 32; off; off >>= 1) l += __shfl_xor(l, off);
        float acc = 0.f;
        for (int tk = 0; tk <= tq; ++tk)
            acc += ps[wave][tk] * __bfloat162float(vb[(size_t)tk * (NKVH * HDIM)]);
        o[((size_t)(b * TSEQ + tq) * NH + h) * HDIM + lane] = __float2bfloat16(acc / l);
    }
}

// ---------------------------------------------------------------------------
// Head projection (fp32, precision-critical path): zp = (x2 * w_norm) @ Wp.
// The final rmsnorm's per-row rsqrt cancels under the subsequent normalize.
// 64x64 tile fp32 sgemm with w_norm folded into the A stage.
// ---------------------------------------------------------------------------
__global__ __launch_bounds__(256) void sgemm_head_kernel(const float* __restrict__ A,
                                                         const float* __restrict__ wn_,
                                                         const float* __restrict__ B,
                                                         float* __restrict__ C,
                                                         int K, int lda, int ldb, int ldc) {
    __shared__ float As[16][68];
    __shared__ float Bs[16][64];
    const int tid = threadIdx.x;
    const int tx = tid & 15, ty = tid >> 4;
    const int bm = blockIdx.y * 64;
    const int bn = blockIdx.x * 64;
    const int ar = tid >> 2, ac = (tid & 3) * 4;
    const int br = tid >> 4, bc = (tid & 15) * 4;
    float acc[4][4] = {};
    for (int k0 = 0; k0 < K; k0 += 16) {
        float4 av = *(const float4*)&A[(size_t)(bm + ar) * lda + k0 + ac];
        float4 wv = *(const float4*)&wn_[k0 + ac];
        float4 bv = *(const float4*)&B[(size_t)(k0 + br) * ldb + bn + bc];
        av.x *= wv.x; av.y *= wv.y; av.z *= wv.z; av.w *= wv.w;
        __syncthreads();
        As[ac + 0][ar] = av.x; As[ac + 1][ar] = av.y;
        As[ac + 2][ar] = av.z; As[ac + 3][ar] = av.w;
        *(float4*)&Bs[br][bc] = bv;
        __syncthreads();
        #pragma unroll
        for (int kk = 0; kk < 16; ++kk) {
            float4 a = *(const float4*)&As[kk][ty * 4];
            float4 b = *(const float4*)&Bs[kk][tx * 4];
            acc[0][0] += a.x * b.x; acc[0][1] += a.x * b.y; acc[0][2] += a.x * b.z; acc[0][3] += a.x * b.w;
            acc[1][0] += a.y * b.x; acc[1][1] += a.y * b.y; acc[1][2] += a.y * b.z; acc[1][3] += a.y * b.w;
            acc[2][0] += a.z * b.x; acc[2][1] += a.z * b.y; acc[2][2] += a.z * b.z; acc[2][3] += a.z * b.w;
            acc[3][0] += a.w * b.x; acc[3][1] += a.w * b.y; acc[3][2] += a.w * b.z; acc[3][3] += a.w * b.w;
        }
    }
    #pragma unroll
    for (int i = 0; i < 4; ++i) {
        const size_t off = (size_t)(bm + ty * 4 + i) * ldc + bn + tx * 4;
        *(float4*)&C[off] = make_float4(acc[i][0], acc[i][1], acc[i][2], acc[i][3]);
    }
}

// ---------------------------------------------------------------------------
// zq = normalize(query @ Wqh) : 64 blocks x 128 threads (fp32)
// ---------------------------------------------------------------------------
__global__ __launch_bounds__(128) void zq_kernel(const float* __restrict__ query,
                                                 const float* __restrict__ Wqh,
                                                 float* __restrict__ zq) {
    const int b = blockIdx.x, j = threadIdx.x;
    const float* qr = query + (size_t)b * QDIMC;
    float acc = 0.f;
    for (int kk = 0; kk < QDIMC; ++kk) acc += qr[kk] * Wqh[(size_t)kk * PDIMC + j];
    float ss = acc * acc;
    #pragma unroll
    for (int off = 32; off; off >>= 1) ss += __shfl_xor(ss, off);
    __shared__ float red[2];
    if ((j & 63) == 0) red[j >> 6] = ss;
    __syncthreads();
    zq[(size_t)b * PDIMC + j] = acc * rsqrtf(red[0] + red[1]);
}

// ---------------------------------------------------------------------------
// out[b,t] = dot(normalize(zp[b,t]), zq[b]) * scale + bias : 1 block/token
// ---------------------------------------------------------------------------
__global__ __launch_bounds__(128) void head_kernel(const float* __restrict__ zp,
                                                   const float* __restrict__ zq,
                                                   const float* __restrict__ scale,
                                                   const float* __restrict__ bias,
                                                   float* __restrict__ out) {
    const int row = blockIdx.x;
    const int b = row / TSEQ;
    const int j = threadIdx.x;
    const float zpv = zp[(size_t)row * PDIMC + j];
    const float zqv = zq[(size_t)b * PDIMC + j];
    float ss = zpv * zpv, dd = zpv * zqv;
    #pragma unroll
    for (int off = 32; off; off >>= 1) { ss += __shfl_xor(ss, off); dd += __shfl_xor(dd, off); }
    __shared__ float rs2[2], rd2[2];
    if ((j & 63) == 0) { rs2[j >> 6] = ss; rd2[j >> 6] = dd; }
    __syncthreads();
    if (j == 0)
        out[row] = (rd2[0] + rd2[1]) * rsqrtf(rs2[0] + rs2[1]) * scale[0] + bias[0];
}

// ---------------------------------------------------------------------------
extern "C" void kernel_launch(void* const* d_in, const int* in_sizes, int n_in,
                              void* d_out, int out_size, void* d_ws, size_t ws_size,
                              hipStream_t stream) {
    const float* x       = (const float*)d_in[0];
    const float* query   = (const float*)d_in[1];
    const float* Wq      = (const float*)d_in[2];
    const float* Wk      = (const float*)d_in[3];
    const float* Wv      = (const float*)d_in[4];
    const float* Wo      = (const float*)d_in[5];
    const float* Wgate   = (const float*)d_in[6];
    const float* Wup     = (const float*)d_in[7];
    const float* Wdown   = (const float*)d_in[8];
    const float* w_ln_in = (const float*)d_in[9];
    const float* w_ln_po = (const float*)d_in[10];
    const float* w_norm  = (const float*)d_in[11];
    const float* Wp      = (const float*)d_in[12];
    const float* Wqh     = (const float*)d_in[13];
    const float* scale   = (const float*)d_in[14];
    const float* bias    = (const float*)d_in[15];
    float* out = (float*)d_out;

    // Workspace: 243.8 MB total (< proven 245 MB budget)
    char* ws = (char*)d_ws;
    __hip_bfloat16* R1 = (__hip_bfloat16*)ws;                 // 51.38MB: h -> o -> h2
    __hip_bfloat16* R2 = (__hip_bfloat16*)(ws + 51380224);    // 51.38MB: q -> g|u|act -> zp,zq
    __hip_bfloat16* R3 = (__hip_bfloat16*)(ws + 102760448);   // 12.85MB: k
    __hip_bfloat16* R4 = (__hip_bfloat16*)(ws + 115605504);   // 12.85MB: v
    float*          x1 = (float*)(ws + 128450560);            // 102.76MB: fp32 residual
    __hip_bfloat16* slot0 = (__hip_bfloat16*)(ws + 231211008);          // 4.19MB
    __hip_bfloat16* slot1 = slot0 + 2097152;                             // 4.19MB
    __hip_bfloat16* slot2 = slot0 + 4194304;                             // 4.19MB
    // note: WqT/WoT (8.39MB) occupy slot0+slot1; WkT/WvT split slot2.
    __hip_bfloat16* g_buf = R2;                         // [NT,1024] bf16
    __hip_bfloat16* u_buf = R2 + (size_t)NT * 1024;     // [NT,1024] bf16
    float* zp = (float*)(ws + 51380224);                // over R2 (act dead)
    float* zq = zp + (size_t)NT * PDIMC;

    // --- attn sublayer ---
    transpose_cast_kernel<<<dim3(64, 64), 256, 0, stream>>>(Wq, slot0, 2048, 2048);
    transpose_cast_kernel<<<dim3(64, 16), 256, 0, stream>>>(Wk, slot2, 2048, 512);
    transpose_cast_kernel<<<dim3(64, 16), 256, 0, stream>>>(Wv, slot2 + 1048576, 2048, 512);
    rmsnorm_bf16_kernel<<<NT, 256, 0, stream>>>(x, w_ln_in, R1);
    mfma_gemm_kernel<0><<<dim3(16, 98), 256, 0, stream>>>(R1, slot0, nullptr, R2, 2048, 2048, 2048, 2048);
    mfma_gemm_kernel<0><<<dim3(4, 98), 256, 0, stream>>>(R1, slot2, nullptr, R3, 2048, 2048, 2048, 512);
    mfma_gemm_kernel<0><<<dim3(4, 98), 256, 0, stream>>>(R1, slot2 + 1048576, nullptr, R4, 2048, 2048, 2048, 512);
    rope_bf16_kernel<<<(NT * NH * 32) / 256, 256, 0, stream>>>(R2, NH, NT * NH * 32);
    rope_bf16_kernel<<<(NT * NKVH * 32) / 256, 256, 0, stream>>>(R3, NKVH, NT * NKVH * 32);
    attn_kernel<<<BATCH * NKVH, 256, 0, stream>>>(R2, R3, R4, R1);   // o -> R1 (h dead)
    transpose_cast_kernel<<<dim3(64, 64), 256, 0, stream>>>(Wo, slot0, 2048, 2048);
    mfma_gemm_kernel<1><<<dim3(16, 98), 256, 0, stream>>>(R1, slot0, x, x1, 2048, 2048, 2048, 2048);
    // --- MLP sublayer (SwiGLU), I chunked by 1024, JIT weight transpose ---
    rmsnorm_bf16_kernel<<<NT, 256, 0, stream>>>(x1, w_ln_po, R1);    // h2 -> R1
    for (int c = 0; c < 8; ++c) {
        transpose_cast_kernel<<<dim3(64, 32), 256, 0, stream>>>(Wgate + (size_t)c * 1024, slot0, 2048, 8192);
        transpose_cast_kernel<<<dim3(64, 32), 256, 0, stream>>>(Wup + (size_t)c * 1024, slot1, 2048, 8192);
        mfma_gemm_kernel<0><<<dim3(8, 98), 256, 0, stream>>>(R1, slot0, nullptr, g_buf, 2048, 2048, 2048, 1024);
        mfma_gemm_kernel<0><<<dim3(8, 98), 256, 0, stream>>>(R1, slot1, nullptr, u_buf, 2048, 2048, 2048, 1024);
        silu_mul_kernel<<<(NT * 1024 / 2 + 255) / 256, 256, 0, stream>>>(g_buf, u_buf, g_buf, NT * 1024 / 2);
        transpose_cast_kernel<<<dim3(32, 64), 256, 0, stream>>>(Wdown + (size_t)c * 1024 * DMODEL, slot2, 1024, 2048);
        mfma_gemm_kernel<2><<<dim3(16, 98), 256, 0, stream>>>(g_buf, slot2, nullptr, x1, 1024, 1024, 1024, 2048);
    }
    // --- head (fp32; final rmsnorm's row scale cancels under normalize) ---
    sgemm_head_kernel<<<dim3(2, 196), 256, 0, stream>>>(x1, w_norm, Wp, zp, 2048, 2048, PDIMC, PDIMC);
    zq_kernel<<<BATCH, 128, 0, stream>>>(query, Wqh, zq);
    head_kernel<<<NT, 128, 0, stream>>>(zp, zq, scale, bias, out);
}